// Round 5
// baseline (350.892 us; speedup 1.0000x reference)
//
#include <hip/hip_runtime.h>
#include <hip/hip_bf16.h>

// B=4, S=2048, D=1024. q=relu(x Wq^T + bq) etc; out = softmax(q k^T) v.
// R5: frag-ready LDS layout. global_load_lds gathers per-lane source
// (row,kchunk) such that LDS holds tiles in exact 32x32x16 MFMA A/B-operand
// order; fragment reads become base + lane*16B (sequential, conflict-free by
// construction). R4's XOR swizzle caused 6.29e6 bank conflicts on the 32x32
// frag reads -- this removes them and the per-fragment address math.
//
// LDS chunk C (16B units) of a 128x32 tile holds source row=(C>>7)*32+(C&31),
// kchunk=((C>>6)&1)*2+((C>>5)&1). Staging: wave w, half j writes chunks
// [j*256+w*64, +64) => lane L fetches row=(w>>1)*32+(L&31) (+64 if j),
// kc=(w&1)*2+(L>>5). Frag read af[mi][h]: chunks ((((w&1)*2+mi)*2+h)*64)+lane.
//
// ws layout (128 MB):
//   [0,16) q | [16,32) k | [32,48) v | [48,64) vt   (bf16)
//   [64,128) logits fp32 (softmax overwrites in-place with bf16 probs)
//   xb aliases [64,80), Wb aliases [80,86) -- consumed by qkv before qk
//   writes logits (stream-ordered).

#define SEQ 2048
#define DIM 1024
#define NB 4
#define MTOT (NB * SEQ)   // 8192

typedef __attribute__((ext_vector_type(8))) short frag_ab;
typedef __attribute__((ext_vector_type(16))) float frag_c16;

__device__ __forceinline__ ushort f2bf(float f) {
    union { float f; unsigned u; } x; x.f = f;
    unsigned r = x.u + 0x7fffu + ((x.u >> 16) & 1u);  // RNE
    return (ushort)(r >> 16);
}

typedef __attribute__((address_space(1))) const unsigned int guint;
typedef __attribute__((address_space(3))) unsigned int luint;

__device__ __forceinline__ void gld_lds16(const void* g, void* l) {
    __builtin_amdgcn_global_load_lds((guint*)g, (luint*)l, 16, 0, 0);
}

// ---------------------------------------------------------------------------
// 128x128-tile bf16 MFMA mainloop, 32x32x16, frag-ready LDS layout.
// A,B pre-offset to tile row 0, K-contiguous (B^T convention).
// ---------------------------------------------------------------------------
__device__ __forceinline__ void gemm_tiles(
    const ushort* __restrict__ A, size_t lda,
    const ushort* __restrict__ B, size_t ldb, int K,
    ushort* As, ushort* Bs, frag_c16 (&acc)[2][2])
{
    const int tid  = threadIdx.x;
    const int wave = tid >> 6;
    const int lane = tid & 63;

    // staging source coords (constant over k-loop)
    const int srow = ((wave >> 1) * 32) + (lane & 31);
    const int skc  = ((wave & 1) * 2) + (lane >> 5);       // 8-elem chunk
    const ushort* pa = A + (size_t)srow * lda + skc * 8;
    const ushort* pb = B + (size_t)srow * ldb + skc * 8;
    ushort* dstA = As + wave * 512;                        // + j*2048
    ushort* dstB = Bs + wave * 512;

    // frag read bases (ushort units), sequential per wave
    const int am = (wave & 1) * 2;   // A sub-block base (rows wm = am*32)
    const int bn = (wave >> 1) * 2;  // B sub-block base

    for (int k0 = 0; k0 < K; k0 += 32) {
        #pragma unroll
        for (int j = 0; j < 2; ++j) {
            gld_lds16(pa + (size_t)j * 64 * lda + k0, dstA + j * 2048);
            gld_lds16(pb + (size_t)j * 64 * ldb + k0, dstB + j * 2048);
        }
        __syncthreads();
        frag_ab af[2][2], bfr[2][2];
        #pragma unroll
        for (int mi = 0; mi < 2; ++mi)
            #pragma unroll
            for (int h = 0; h < 2; ++h)
                af[mi][h] = *(const frag_ab*)&As[((am + mi) * 2 + h) * 512 + lane * 8];
        #pragma unroll
        for (int ni = 0; ni < 2; ++ni)
            #pragma unroll
            for (int h = 0; h < 2; ++h)
                bfr[ni][h] = *(const frag_ab*)&Bs[((bn + ni) * 2 + h) * 512 + lane * 8];
        #pragma unroll
        for (int h = 0; h < 2; ++h)
            #pragma unroll
            for (int mi = 0; mi < 2; ++mi)
                #pragma unroll
                for (int ni = 0; ni < 2; ++ni)
                    acc[mi][ni] = __builtin_amdgcn_mfma_f32_32x32x16_bf16(
                        af[mi][h], bfr[ni][h], acc[mi][ni], 0, 0, 0);
        __syncthreads();
    }
}

// C/D layout (32x32): col = lane&31, row = (reg&3) + 8*(reg>>2) + 4*(lane>>5)

// ---------------------------------------------------------------------------
// fp32 -> bf16 converter, x + 3 weights in one launch (memory-bound)
// ---------------------------------------------------------------------------
#define NX4 (MTOT * DIM / 4)          // 2M float4 for x
#define NW4 (DIM * DIM / 4)           // 256K float4 per W
__global__ __launch_bounds__(256) void cvt_kernel(
    const float* __restrict__ x,
    const float* __restrict__ Wq, const float* __restrict__ Wk,
    const float* __restrict__ Wv,
    ushort* __restrict__ xb, ushort* __restrict__ Wb)
{
    size_t i = (size_t)blockIdx.x * 256 + threadIdx.x;
    const float* src; ushort* dst; size_t idx;
    if (i < NX4) { src = x; dst = xb; idx = i; }
    else {
        size_t j = i - NX4;
        int w = (int)(j >> 18);               // j / NW4
        idx = j & (NW4 - 1);
        src = w == 0 ? Wq : (w == 1 ? Wk : Wv);
        dst = Wb + (size_t)w * DIM * DIM;
    }
    float4 f = ((const float4*)src)[idx];
    ushort4 u; u.x = f2bf(f.x); u.y = f2bf(f.y); u.z = f2bf(f.z); u.w = f2bf(f.w);
    ((ushort4*)dst)[idx] = u;
}

// ---------------------------------------------------------------------------
// Kernel 1: q/k/v = relu(x W^T + b) -> bf16.  grid (64, 8, 3), block 256
// ---------------------------------------------------------------------------
__global__ __launch_bounds__(256) void qkv_kernel(
    const ushort* __restrict__ xb, const ushort* __restrict__ Wb,
    const float* __restrict__ bq, const float* __restrict__ bk,
    const float* __restrict__ bv,
    ushort* __restrict__ q, ushort* __restrict__ k, ushort* __restrict__ v)
{
    const float* bias; ushort* out;
    if (blockIdx.z == 0)      { bias = bq; out = q; }
    else if (blockIdx.z == 1) { bias = bk; out = k; }
    else                      { bias = bv; out = v; }
    const ushort* W = Wb + (size_t)blockIdx.z * DIM * DIM;

    __shared__ ushort As[128 * 32];
    __shared__ ushort Bs[128 * 32];

    const int tid  = threadIdx.x;
    const int wave = tid >> 6;
    const int lane = tid & 63;
    const int l32  = lane & 31;
    const int half = lane >> 5;
    const int m0 = blockIdx.x * 128;
    const int n0 = blockIdx.y * 128;
    const int wm = (wave & 1) * 64;
    const int wn = (wave >> 1) * 64;

    frag_c16 acc[2][2] = {};
    gemm_tiles(xb + (size_t)m0 * DIM, DIM, W + (size_t)n0 * DIM, DIM, DIM,
               As, Bs, acc);

    #pragma unroll
    for (int ni = 0; ni < 2; ++ni) {
        int col = n0 + wn + ni * 32 + l32;
        float bb = bias[col];
        #pragma unroll
        for (int mi = 0; mi < 2; ++mi)
            #pragma unroll
            for (int r = 0; r < 16; ++r) {
                int row = m0 + wm + mi * 32 + (r & 3) + 8 * (r >> 2) + 4 * half;
                float val = acc[mi][ni][r] + bb;
                val = val > 0.0f ? val : 0.0f;
                out[(size_t)row * DIM + col] = f2bf(val);
            }
    }
}

// ---------------------------------------------------------------------------
// Kernel 2: vt[bz][o][s] = v[bz][s][o]  (bf16 64x64 LDS transpose)
// ---------------------------------------------------------------------------
__global__ __launch_bounds__(256) void transpose_v(
    const ushort* __restrict__ v, ushort* __restrict__ vt)
{
    __shared__ ushort T[64][72];
    const int bz = blockIdx.z;
    const int s0 = blockIdx.x * 64;
    const int o0 = blockIdx.y * 64;
    const int t  = threadIdx.x;

    #pragma unroll
    for (int p = 0; p < 4; ++p) {
        int sl = p * 16 + (t >> 4);
        int o4 = (t & 15) * 4;
        ushort4 u = *(const ushort4*)&v[(size_t)(bz * SEQ + s0 + sl) * DIM + o0 + o4];
        *(ushort4*)&T[sl][o4] = u;
    }
    __syncthreads();
    #pragma unroll
    for (int p = 0; p < 4; ++p) {
        int ol = p * 16 + (t >> 4);
        int s4 = (t & 15) * 4;
        ushort4 u;
        u.x = T[s4 + 0][ol]; u.y = T[s4 + 1][ol];
        u.z = T[s4 + 2][ol]; u.w = T[s4 + 3][ol];
        *(ushort4*)&vt[(size_t)(bz * DIM + o0 + ol) * SEQ + s0 + s4] = u;
    }
}

// ---------------------------------------------------------------------------
// Kernel 3: logits = q k^T (fp32).  grid (16,16,4)
// ---------------------------------------------------------------------------
__global__ __launch_bounds__(256) void qk_kernel(
    const ushort* __restrict__ q, const ushort* __restrict__ kk,
    float* __restrict__ logits)
{
    __shared__ ushort As[128 * 32];
    __shared__ ushort Bs[128 * 32];

    const int tid  = threadIdx.x;
    const int wave = tid >> 6;
    const int lane = tid & 63;
    const int l32  = lane & 31;
    const int half = lane >> 5;
    const int bz = blockIdx.z;
    const int m0 = blockIdx.x * 128;
    const int n0 = blockIdx.y * 128;
    const int wm = (wave & 1) * 64;
    const int wn = (wave >> 1) * 64;
    const size_t base = (size_t)bz * SEQ;

    frag_c16 acc[2][2] = {};
    gemm_tiles(q + (base + m0) * DIM, DIM, kk + (base + n0) * DIM, DIM, DIM,
               As, Bs, acc);

    #pragma unroll
    for (int mi = 0; mi < 2; ++mi)
        #pragma unroll
        for (int r = 0; r < 16; ++r) {
            int row = m0 + wm + mi * 32 + (r & 3) + 8 * (r >> 2) + 4 * half;
            #pragma unroll
            for (int ni = 0; ni < 2; ++ni) {
                int col = n0 + wn + ni * 32 + l32;
                logits[(base + row) * SEQ + col] = acc[mi][ni][r];
            }
        }
}

// ---------------------------------------------------------------------------
// Kernel 4: row softmax over 2048 fp32, write bf16 probs in-place.
// ---------------------------------------------------------------------------
__global__ __launch_bounds__(256) void softmax_kernel(float* __restrict__ logits)
{
    float* p = logits + (size_t)blockIdx.x * SEQ;
    const int t = threadIdx.x;
    const int wave = t >> 6, lane = t & 63;

    float4 a = ((const float4*)p)[t];
    float4 b = ((const float4*)p)[t + 256];

    float m = fmaxf(fmaxf(fmaxf(a.x, a.y), fmaxf(a.z, a.w)),
                    fmaxf(fmaxf(b.x, b.y), fmaxf(b.z, b.w)));
    #pragma unroll
    for (int off = 32; off; off >>= 1) m = fmaxf(m, __shfl_down(m, off, 64));

    __shared__ float red[4];
    if (lane == 0) red[wave] = m;
    __syncthreads();
    m = fmaxf(fmaxf(red[0], red[1]), fmaxf(red[2], red[3]));

    a.x = __expf(a.x - m); a.y = __expf(a.y - m);
    a.z = __expf(a.z - m); a.w = __expf(a.w - m);
    b.x = __expf(b.x - m); b.y = __expf(b.y - m);
    b.z = __expf(b.z - m); b.w = __expf(b.w - m);

    float s = (a.x + a.y + a.z + a.w) + (b.x + b.y + b.z + b.w);
    #pragma unroll
    for (int off = 32; off; off >>= 1) s += __shfl_down(s, off, 64);
    __syncthreads();
    if (lane == 0) red[wave] = s;
    __syncthreads();
    s = red[0] + red[1] + red[2] + red[3];
    float inv = 1.0f / s;

    ushort* o = (ushort*)p;
    ushort4 u0, u1;
    u0.x = f2bf(a.x * inv); u0.y = f2bf(a.y * inv);
    u0.z = f2bf(a.z * inv); u0.w = f2bf(a.w * inv);
    u1.x = f2bf(b.x * inv); u1.y = f2bf(b.y * inv);
    u1.z = f2bf(b.z * inv); u1.w = f2bf(b.w * inv);
    ((ushort4*)o)[t]       = u0;
    ((ushort4*)o)[t + 256] = u1;
}

// ---------------------------------------------------------------------------
// Kernel 5: out = P vt^T (fp32). P rows stride 4096 ushorts. grid (16,8,4)
// ---------------------------------------------------------------------------
__global__ __launch_bounds__(256) void pv_kernel(
    const ushort* __restrict__ probs, const ushort* __restrict__ vt,
    float* __restrict__ out)
{
    __shared__ ushort As[128 * 32];
    __shared__ ushort Bs[128 * 32];

    const int tid  = threadIdx.x;
    const int wave = tid >> 6;
    const int lane = tid & 63;
    const int l32  = lane & 31;
    const int half = lane >> 5;
    const int bz = blockIdx.z;
    const int m0 = blockIdx.x * 128;
    const int n0 = blockIdx.y * 128;
    const int wm = (wave & 1) * 64;
    const int wn = (wave >> 1) * 64;

    frag_c16 acc[2][2] = {};
    gemm_tiles(probs + ((size_t)(bz * SEQ + m0)) * 4096, 4096,
               vt + ((size_t)(bz * DIM + n0)) * SEQ, SEQ, SEQ,
               As, Bs, acc);

    #pragma unroll
    for (int mi = 0; mi < 2; ++mi)
        #pragma unroll
        for (int r = 0; r < 16; ++r) {
            int row = m0 + wm + mi * 32 + (r & 3) + 8 * (r >> 2) + 4 * half;
            #pragma unroll
            for (int ni = 0; ni < 2; ++ni) {
                int col = n0 + wn + ni * 32 + l32;
                out[((size_t)(bz * SEQ + row)) * DIM + col] = acc[mi][ni][r];
            }
        }
}

// ---------------------------------------------------------------------------
extern "C" void kernel_launch(void* const* d_in, const int* in_sizes, int n_in,
                              void* d_out, int out_size, void* d_ws, size_t ws_size,
                              hipStream_t stream)
{
    const float* x  = (const float*)d_in[0];
    const float* Wq = (const float*)d_in[1];
    const float* bq = (const float*)d_in[2];
    const float* Wk = (const float*)d_in[3];
    const float* bk = (const float*)d_in[4];
    const float* Wv = (const float*)d_in[5];
    const float* bv = (const float*)d_in[6];
    float* out = (float*)d_out;

    char* ws = (char*)d_ws;
    ushort* q      = (ushort*)(ws);                           // 16 MB
    ushort* kk     = (ushort*)(ws + ((size_t)16 << 20));      // 16 MB
    ushort* v      = (ushort*)(ws + ((size_t)32 << 20));      // 16 MB
    ushort* vt     = (ushort*)(ws + ((size_t)48 << 20));      // 16 MB
    float*  logits = (float*) (ws + ((size_t)64 << 20));      // 64 MB
    ushort* xb     = (ushort*)(ws + ((size_t)64 << 20));      // aliases logits
    ushort* Wb     = (ushort*)(ws + ((size_t)80 << 20));      // aliases logits

    cvt_kernel<<<dim3((NX4 + 3 * NW4) / 256), 256, 0, stream>>>(
        x, Wq, Wk, Wv, xb, Wb);

    qkv_kernel<<<dim3(MTOT / 128, DIM / 128, 3), 256, 0, stream>>>(
        xb, Wb, bq, bk, bv, q, kk, v);
    transpose_v<<<dim3(SEQ / 64, DIM / 64, NB), 256, 0, stream>>>(v, vt);
    qk_kernel<<<dim3(SEQ / 128, SEQ / 128, NB), 256, 0, stream>>>(q, kk, logits);
    softmax_kernel<<<NB * SEQ, 256, 0, stream>>>(logits);
    pv_kernel<<<dim3(SEQ / 128, DIM / 128, NB), 256, 0, stream>>>(
        (const ushort*)logits, vt, out);
}

// Round 6
// 280.270 us; speedup vs baseline: 1.2520x; 1.2520x over previous
//
#include <hip/hip_runtime.h>
#include <hip/hip_bf16.h>

// B=4, S=2048, D=1024. q=relu(x Wq^T + bq) etc; out = softmax(q k^T) v.
// R6: revert GEMM to R4 (32x32x16 MFMA + row-major XOR-swizzled staging --
// empirically best at 277us; R5's "conflict-free" gather layout halved L2
// request efficiency and regressed). New: drop transpose_v -- the V slice of
// qkv_kernel stores its output tile directly transposed into vt.
//
// ws layout (128 MB):
//   [0,16) q | [16,32) k | [32,48) vt   (bf16)
//   [64,128) logits fp32 (softmax overwrites in-place with bf16 probs)
//   xb aliases [64,80), Wb aliases [80,86) -- consumed by qkv before qk
//   writes logits (stream-ordered).

#define SEQ 2048
#define DIM 1024
#define NB 4
#define MTOT (NB * SEQ)   // 8192

typedef __attribute__((ext_vector_type(8))) short frag_ab;
typedef __attribute__((ext_vector_type(16))) float frag_c16;

__device__ __forceinline__ ushort f2bf(float f) {
    union { float f; unsigned u; } x; x.f = f;
    unsigned r = x.u + 0x7fffu + ((x.u >> 16) & 1u);  // RNE
    return (ushort)(r >> 16);
}

typedef __attribute__((address_space(1))) const unsigned int guint;
typedef __attribute__((address_space(3))) unsigned int luint;

__device__ __forceinline__ void gld_lds16(const void* g, void* l) {
    __builtin_amdgcn_global_load_lds((guint*)g, (luint*)l, 16, 0, 0);
}

// ---------------------------------------------------------------------------
// 128x128-tile bf16 MFMA mainloop, 32x32x16 shape (R4 version).
// LDS tiles 128x32 unpadded; global 16B-chunk cg of row r stored at physical
// chunk cg ^ ((r>>1)&3). Wave w owns 64x64 subtile (wm,wn) as 2x2 32x32.
// ---------------------------------------------------------------------------
__device__ __forceinline__ void gemm_tiles(
    const ushort* __restrict__ A, size_t lda,
    const ushort* __restrict__ B, size_t ldb, int K,
    ushort* As, ushort* Bs, frag_c16 (&acc)[2][2])
{
    const int tid  = threadIdx.x;
    const int wave = tid >> 6;
    const int lane = tid & 63;
    const int l32  = lane & 31;
    const int half = lane >> 5;
    const int sr = wave * 16 + (lane >> 2);   // staging row (within 64-row half)
    const int sc = lane & 3;                  // staging physical chunk slot
    const int wm = (wave & 1) * 64;
    const int wn = (wave >> 1) * 64;

    for (int k0 = 0; k0 < K; k0 += 32) {
        #pragma unroll
        for (int j = 0; j < 2; ++j) {
            int row = j * 64 + sr;
            int cg  = sc ^ ((row >> 1) & 3);          // swizzled source chunk
            ushort* la = As + (j * 64 + wave * 16) * 32;  // wave-uniform base
            ushort* lb = Bs + (j * 64 + wave * 16) * 32;
            gld_lds16(A + (size_t)row * lda + k0 + cg * 8, la);
            gld_lds16(B + (size_t)row * ldb + k0 + cg * 8, lb);
        }
        __syncthreads();
        frag_ab af[2][2], bfr[2][2];
        #pragma unroll
        for (int mi = 0; mi < 2; ++mi) {
            int row = wm + mi * 32 + l32;
            int sw = (row >> 1) & 3;
            #pragma unroll
            for (int h = 0; h < 2; ++h) {
                int c = (h * 2 + half) ^ sw;
                af[mi][h] = *(const frag_ab*)&As[row * 32 + c * 8];
            }
        }
        #pragma unroll
        for (int ni = 0; ni < 2; ++ni) {
            int row = wn + ni * 32 + l32;
            int sw = (row >> 1) & 3;
            #pragma unroll
            for (int h = 0; h < 2; ++h) {
                int c = (h * 2 + half) ^ sw;
                bfr[ni][h] = *(const frag_ab*)&Bs[row * 32 + c * 8];
            }
        }
        #pragma unroll
        for (int h = 0; h < 2; ++h)
            #pragma unroll
            for (int mi = 0; mi < 2; ++mi)
                #pragma unroll
                for (int ni = 0; ni < 2; ++ni)
                    acc[mi][ni] = __builtin_amdgcn_mfma_f32_32x32x16_bf16(
                        af[mi][h], bfr[ni][h], acc[mi][ni], 0, 0, 0);
        __syncthreads();
    }
}

// C/D layout (32x32): col = lane&31, row = (reg&3) + 8*(reg>>2) + 4*(lane>>5)

// ---------------------------------------------------------------------------
// fp32 -> bf16 converter, x + 3 weights in one launch (memory-bound)
// ---------------------------------------------------------------------------
#define NX4 (MTOT * DIM / 4)          // 2M float4 for x
#define NW4 (DIM * DIM / 4)           // 256K float4 per W
__global__ __launch_bounds__(256) void cvt_kernel(
    const float* __restrict__ x,
    const float* __restrict__ Wq, const float* __restrict__ Wk,
    const float* __restrict__ Wv,
    ushort* __restrict__ xb, ushort* __restrict__ Wb)
{
    size_t i = (size_t)blockIdx.x * 256 + threadIdx.x;
    const float* src; ushort* dst; size_t idx;
    if (i < NX4) { src = x; dst = xb; idx = i; }
    else {
        size_t j = i - NX4;
        int w = (int)(j >> 18);               // j / NW4
        idx = j & (NW4 - 1);
        src = w == 0 ? Wq : (w == 1 ? Wk : Wv);
        dst = Wb + (size_t)w * DIM * DIM;
    }
    float4 f = ((const float4*)src)[idx];
    ushort4 u; u.x = f2bf(f.x); u.y = f2bf(f.y); u.z = f2bf(f.z); u.w = f2bf(f.w);
    ((ushort4*)dst)[idx] = u;
}

// ---------------------------------------------------------------------------
// Kernel 1: q/k = relu(x W^T + b) -> bf16 row-major; v slice stores directly
// transposed into vt[bz][o][s].  grid (64, 8, 3), block 256
// ---------------------------------------------------------------------------
__global__ __launch_bounds__(256) void qkv_kernel(
    const ushort* __restrict__ xb, const ushort* __restrict__ Wb,
    const float* __restrict__ bq, const float* __restrict__ bk,
    const float* __restrict__ bv,
    ushort* __restrict__ q, ushort* __restrict__ k, ushort* __restrict__ vt)
{
    const float* bias; ushort* out;
    if (blockIdx.z == 0)      { bias = bq; out = q; }
    else if (blockIdx.z == 1) { bias = bk; out = k; }
    else                      { bias = bv; out = vt; }
    const ushort* W = Wb + (size_t)blockIdx.z * DIM * DIM;

    __shared__ ushort As[128 * 32];
    __shared__ ushort Bs[128 * 32];

    const int tid  = threadIdx.x;
    const int wave = tid >> 6;
    const int lane = tid & 63;
    const int l32  = lane & 31;
    const int half = lane >> 5;
    const int m0 = blockIdx.x * 128;
    const int n0 = blockIdx.y * 128;
    const int wm = (wave & 1) * 64;
    const int wn = (wave >> 1) * 64;

    frag_c16 acc[2][2] = {};
    gemm_tiles(xb + (size_t)m0 * DIM, DIM, W + (size_t)n0 * DIM, DIM, DIM,
               As, Bs, acc);

    if (blockIdx.z < 2) {
        #pragma unroll
        for (int ni = 0; ni < 2; ++ni) {
            int col = n0 + wn + ni * 32 + l32;
            float bb = bias[col];
            #pragma unroll
            for (int mi = 0; mi < 2; ++mi)
                #pragma unroll
                for (int r = 0; r < 16; ++r) {
                    int row = m0 + wm + mi * 32 + (r & 3) + 8 * (r >> 2) + 4 * half;
                    float val = acc[mi][ni][r] + bb;
                    val = val > 0.0f ? val : 0.0f;
                    out[(size_t)row * DIM + col] = f2bf(val);
                }
        }
    } else {
        // vt[bz][col][s]: pack 4 consecutive s (r&3) into one 8B store.
        const int bz = m0 >> 11;                 // batch of this row-tile
        const int sb = (m0 & (SEQ - 1)) + wm;    // s base within batch
        #pragma unroll
        for (int ni = 0; ni < 2; ++ni) {
            int col = n0 + wn + ni * 32 + l32;
            float bb = bias[col];
            ushort* vcol = out + ((size_t)bz * DIM + col) * SEQ;
            #pragma unroll
            for (int mi = 0; mi < 2; ++mi)
                #pragma unroll
                for (int g = 0; g < 4; ++g) {
                    int s0 = sb + mi * 32 + 8 * g + 4 * half;
                    ushort4 u;
                    float v0 = acc[mi][ni][4 * g + 0] + bb;
                    float v1 = acc[mi][ni][4 * g + 1] + bb;
                    float v2 = acc[mi][ni][4 * g + 2] + bb;
                    float v3 = acc[mi][ni][4 * g + 3] + bb;
                    u.x = f2bf(v0 > 0.0f ? v0 : 0.0f);
                    u.y = f2bf(v1 > 0.0f ? v1 : 0.0f);
                    u.z = f2bf(v2 > 0.0f ? v2 : 0.0f);
                    u.w = f2bf(v3 > 0.0f ? v3 : 0.0f);
                    *(ushort4*)&vcol[s0] = u;
                }
        }
    }
}

// ---------------------------------------------------------------------------
// Kernel 3: logits = q k^T (fp32).  grid (16,16,4)
// ---------------------------------------------------------------------------
__global__ __launch_bounds__(256) void qk_kernel(
    const ushort* __restrict__ q, const ushort* __restrict__ kk,
    float* __restrict__ logits)
{
    __shared__ ushort As[128 * 32];
    __shared__ ushort Bs[128 * 32];

    const int tid  = threadIdx.x;
    const int wave = tid >> 6;
    const int lane = tid & 63;
    const int l32  = lane & 31;
    const int half = lane >> 5;
    const int bz = blockIdx.z;
    const int m0 = blockIdx.x * 128;
    const int n0 = blockIdx.y * 128;
    const int wm = (wave & 1) * 64;
    const int wn = (wave >> 1) * 64;
    const size_t base = (size_t)bz * SEQ;

    frag_c16 acc[2][2] = {};
    gemm_tiles(q + (base + m0) * DIM, DIM, kk + (base + n0) * DIM, DIM, DIM,
               As, Bs, acc);

    #pragma unroll
    for (int mi = 0; mi < 2; ++mi)
        #pragma unroll
        for (int r = 0; r < 16; ++r) {
            int row = m0 + wm + mi * 32 + (r & 3) + 8 * (r >> 2) + 4 * half;
            #pragma unroll
            for (int ni = 0; ni < 2; ++ni) {
                int col = n0 + wn + ni * 32 + l32;
                logits[(base + row) * SEQ + col] = acc[mi][ni][r];
            }
        }
}

// ---------------------------------------------------------------------------
// Kernel 4: row softmax over 2048 fp32, write bf16 probs in-place.
// ---------------------------------------------------------------------------
__global__ __launch_bounds__(256) void softmax_kernel(float* __restrict__ logits)
{
    float* p = logits + (size_t)blockIdx.x * SEQ;
    const int t = threadIdx.x;
    const int wave = t >> 6, lane = t & 63;

    float4 a = ((const float4*)p)[t];
    float4 b = ((const float4*)p)[t + 256];

    float m = fmaxf(fmaxf(fmaxf(a.x, a.y), fmaxf(a.z, a.w)),
                    fmaxf(fmaxf(b.x, b.y), fmaxf(b.z, b.w)));
    #pragma unroll
    for (int off = 32; off; off >>= 1) m = fmaxf(m, __shfl_down(m, off, 64));

    __shared__ float red[4];
    if (lane == 0) red[wave] = m;
    __syncthreads();
    m = fmaxf(fmaxf(red[0], red[1]), fmaxf(red[2], red[3]));

    a.x = __expf(a.x - m); a.y = __expf(a.y - m);
    a.z = __expf(a.z - m); a.w = __expf(a.w - m);
    b.x = __expf(b.x - m); b.y = __expf(b.y - m);
    b.z = __expf(b.z - m); b.w = __expf(b.w - m);

    float s = (a.x + a.y + a.z + a.w) + (b.x + b.y + b.z + b.w);
    #pragma unroll
    for (int off = 32; off; off >>= 1) s += __shfl_down(s, off, 64);
    __syncthreads();
    if (lane == 0) red[wave] = s;
    __syncthreads();
    s = red[0] + red[1] + red[2] + red[3];
    float inv = 1.0f / s;

    ushort* o = (ushort*)p;
    ushort4 u0, u1;
    u0.x = f2bf(a.x * inv); u0.y = f2bf(a.y * inv);
    u0.z = f2bf(a.z * inv); u0.w = f2bf(a.w * inv);
    u1.x = f2bf(b.x * inv); u1.y = f2bf(b.y * inv);
    u1.z = f2bf(b.z * inv); u1.w = f2bf(b.w * inv);
    ((ushort4*)o)[t]       = u0;
    ((ushort4*)o)[t + 256] = u1;
}

// ---------------------------------------------------------------------------
// Kernel 5: out = P vt^T (fp32). P rows stride 4096 ushorts. grid (16,8,4)
// ---------------------------------------------------------------------------
__global__ __launch_bounds__(256) void pv_kernel(
    const ushort* __restrict__ probs, const ushort* __restrict__ vt,
    float* __restrict__ out)
{
    __shared__ ushort As[128 * 32];
    __shared__ ushort Bs[128 * 32];

    const int tid  = threadIdx.x;
    const int wave = tid >> 6;
    const int lane = tid & 63;
    const int l32  = lane & 31;
    const int half = lane >> 5;
    const int bz = blockIdx.z;
    const int m0 = blockIdx.x * 128;
    const int n0 = blockIdx.y * 128;
    const int wm = (wave & 1) * 64;
    const int wn = (wave >> 1) * 64;

    frag_c16 acc[2][2] = {};
    gemm_tiles(probs + ((size_t)(bz * SEQ + m0)) * 4096, 4096,
               vt + ((size_t)(bz * DIM + n0)) * SEQ, SEQ, SEQ,
               As, Bs, acc);

    #pragma unroll
    for (int mi = 0; mi < 2; ++mi)
        #pragma unroll
        for (int r = 0; r < 16; ++r) {
            int row = m0 + wm + mi * 32 + (r & 3) + 8 * (r >> 2) + 4 * half;
            #pragma unroll
            for (int ni = 0; ni < 2; ++ni) {
                int col = n0 + wn + ni * 32 + l32;
                out[((size_t)(bz * SEQ + row)) * DIM + col] = acc[mi][ni][r];
            }
        }
}

// ---------------------------------------------------------------------------
extern "C" void kernel_launch(void* const* d_in, const int* in_sizes, int n_in,
                              void* d_out, int out_size, void* d_ws, size_t ws_size,
                              hipStream_t stream)
{
    const float* x  = (const float*)d_in[0];
    const float* Wq = (const float*)d_in[1];
    const float* bq = (const float*)d_in[2];
    const float* Wk = (const float*)d_in[3];
    const float* bk = (const float*)d_in[4];
    const float* Wv = (const float*)d_in[5];
    const float* bv = (const float*)d_in[6];
    float* out = (float*)d_out;

    char* ws = (char*)d_ws;
    ushort* q      = (ushort*)(ws);                           // 16 MB
    ushort* kk     = (ushort*)(ws + ((size_t)16 << 20));      // 16 MB
    ushort* vt     = (ushort*)(ws + ((size_t)32 << 20));      // 16 MB
    float*  logits = (float*) (ws + ((size_t)64 << 20));      // 64 MB
    ushort* xb     = (ushort*)(ws + ((size_t)64 << 20));      // aliases logits
    ushort* Wb     = (ushort*)(ws + ((size_t)80 << 20));      // aliases logits

    cvt_kernel<<<dim3((NX4 + 3 * NW4) / 256), 256, 0, stream>>>(
        x, Wq, Wk, Wv, xb, Wb);

    qkv_kernel<<<dim3(MTOT / 128, DIM / 128, 3), 256, 0, stream>>>(
        xb, Wb, bq, bk, bv, q, kk, vt);
    qk_kernel<<<dim3(SEQ / 128, SEQ / 128, NB), 256, 0, stream>>>(q, kk, logits);
    softmax_kernel<<<NB * SEQ, 256, 0, stream>>>(logits);
    pv_kernel<<<dim3(SEQ / 128, DIM / 128, NB), 256, 0, stream>>>(
        (const ushort*)logits, vt, out);
}